// Round 3
// baseline (346.692 us; speedup 1.0000x reference)
//
#include <hip/hip_runtime.h>
#include <hip/hip_bf16.h>

#define NC 100000
#define NU 100000
#define NE 1600000
#define DC 256
#define DU 128
#define HID 128
#define OUTD 64

#define BSHIFT 9
#define BRANGE 512
#define NBUCK ((NC + BRANGE - 1) / BRANGE)   // 196
#define BCAP 10240
#define EPB 8192
#define ABLK ((NE + EPB - 1) / EPB)          // 196

#define TM 32                                // GEMM tile rows
#define NT_C (NC / TM)                       // 3125 (exact)
#define NT_U (NU / TM)                       // 3125 (exact)

// persistent-block grid: 2 blocks/CU, weighted 2:1 by tile bytes
#define NBC 342
#define NBU 170

#define ABUF_STRIDE 32768                    // bytes per A LDS buffer (content-sized)
#define SH (HID + 8)                         // h_s row stride (shorts)

typedef __attribute__((ext_vector_type(8))) short bf16x8;
typedef __attribute__((ext_vector_type(4))) float f32x4;

// RNE float->bf16 (finite inputs)
__device__ inline unsigned short f2b(float f) {
    unsigned int u = __float_as_uint(f);
    u += 0x7fffu + ((u >> 16) & 1u);
    return (unsigned short)(u >> 16);
}

// async global->LDS, 16B per lane; LDS dest is wave-uniform base + lane*16
__device__ __forceinline__ void gload_lds16(const float* g, void* l) {
    __builtin_amdgcn_global_load_lds(
        (const __attribute__((address_space(1))) void*)g,
        (__attribute__((address_space(3))) void*)l, 16, 0, 0);
}

// ---------------------------------------------------------------------------
// K0: Wlo_p = packed (Wl@Wo) bf16, Wro_p = packed (Wr@Wo) bf16, b2 = bl@Wo+bo.
// Packed B-fragment layout for GEMM2 (16x16x32 mfma):
//   element W2[k][f]: idx = ((w*4 + ks)*64 + quad*16 + l16)*8 + e
//   with f = w*16+l16, k = ks*32 + quad*8 + e.
// ---------------------------------------------------------------------------
__global__ void prep_kernel(const float* __restrict__ Wl, const float* __restrict__ bl,
                            const float* __restrict__ Wr, const float* __restrict__ Wo,
                            const float* __restrict__ bo,
                            __hip_bfloat16* __restrict__ Wlo_p,
                            __hip_bfloat16* __restrict__ Wro_p,
                            float* __restrict__ b2) {
    const int k = blockIdx.x;   // 0..127 (HID)
    const int f = threadIdx.x;  // 0..63  (OUTD)
    float a0 = 0.f, a1 = 0.f;
    for (int m = 0; m < HID; ++m) {
        float wo = Wo[m * OUTD + f];
        a0 = fmaf(Wl[k * HID + m], wo, a0);
        a1 = fmaf(Wr[k * HID + m], wo, a1);
    }
    const int wv = f >> 4, l16 = f & 15;
    const int ks = k >> 5, quad = (k >> 3) & 3, e = k & 7;
    const int idx = (((wv * 4 + ks) * 64) + quad * 16 + l16) * 8 + e;
    Wlo_p[idx] = __float2bfloat16(a0);
    Wro_p[idx] = __float2bfloat16(a1);
    if (k == 0) {
        float s = bo[f];
        for (int m = 0; m < HID; ++m) s = fmaf(bl[m], Wo[m * OUTD + f], s);
        b2[f] = s;
    }
}

// ---------------------------------------------------------------------------
// K0b: pack input-proj weight W[K][HID] into GEMM1 B-fragment-linear layout:
//   element W[k][j]: idx = (((j>>4)*(K/32) + (k>>5))*64 + ((k>>3)&3)*16 + (j&15))*8 + (k&7)
// ---------------------------------------------------------------------------
__global__ void pack_w(const float* __restrict__ W, __hip_bfloat16* __restrict__ Wp,
                       int K) {
    int i = blockIdx.x * blockDim.x + threadIdx.x;
    int total = K * HID;
    if (i >= total) return;
    int j = i % HID, k = i / HID;
    int nks = K >> 5;
    int idx = (((j >> 4) * nks + (k >> 5)) * 64 + ((k >> 3) & 3) * 16 + (j & 15)) * 8 +
              (k & 7);
    Wp[idx] = __float2bfloat16(W[k * HID + j]);
}

// ---------------------------------------------------------------------------
// Device GEMM path: p = relu(x @ W1 + b1) @ W2 (+bias2)
// m97/m201-style pipeline:
//   - fp32 x staged by global_load_lds into double-buffered LDS (no VGPR trip)
//   - global source addresses pre-XOR-swizzled (chunk L ^= (row&31)) so the
//     linear gll dest yields a bank-conflict-free layout for the frag reads
//   - raw s_barrier + counted vmcnt(NCH): next tile's loads in flight across
//     both barriers, hidden under GEMM1+GEMM2
//   - fp32->bf16 RNE at fragment-build time (bit-identical to prior rounds)
// ---------------------------------------------------------------------------
template <int DIN, bool BF16OUT>
__device__ __forceinline__ void gemm_path(const float* __restrict__ x,
                                          const __hip_bfloat16* __restrict__ W1p,
                                          const float* __restrict__ b1,
                                          const __hip_bfloat16* __restrict__ W2p,
                                          const float* __restrict__ bias2,
                                          void* __restrict__ outp,
                                          int ntiles, int blk, int nblk,
                                          char* __restrict__ sm) {
    constexpr int NKS = DIN / 32;        // GEMM1 K-steps
    constexpr int NCH = DIN / 32;        // gll issues per thread per tile
    constexpr int CRB = (DIN == 256) ? 6 : 5;   // log2(16B chunks per row)
    short* h_s = (short*)(sm + 2 * ABUF_STRIDE);

    const int t = threadIdx.x;
    const int w = t >> 6, lane = t & 63;
    const int quad = lane >> 4, l16 = lane & 15;

    // ---- persistent B fragments (packed, coalesced, once per block) ----
    bf16x8 b1f[2][NKS];
#pragma unroll
    for (int ntl = 0; ntl < 2; ++ntl)
#pragma unroll
        for (int ks = 0; ks < NKS; ++ks)
            b1f[ntl][ks] =
                *(const bf16x8*)&W1p[(size_t)(((2 * w + ntl) * NKS + ks) * 64 + lane) * 8];
    bf16x8 b2f[HID / 32];
#pragma unroll
    for (int ks = 0; ks < HID / 32; ++ks)
        b2f[ks] = *(const bf16x8*)&W2p[(size_t)((w * 4 + ks) * 64 + lane) * 8];
    const float bb1_0 = b1[w * 32 + l16];
    const float bb1_1 = b1[w * 32 + 16 + l16];
    const float bb2 = BF16OUT ? 0.f : bias2[w * 16 + l16];

    // stage tile -> LDS buffer `buf` (async, pre-swizzled global source)
    auto stage = [&](int tile, int buf) {
        const float* gt = x + (size_t)tile * TM * DIN;
#pragma unroll
        for (int k = 0; k < NCH; ++k) {
            int L = (k * 4 + w) * 64 + lane;          // linear 16B-chunk index
            int g = L ^ ((L >> CRB) & 31);            // inverse swizzle on source
            gload_lds16(gt + g * 4, sm + buf * ABUF_STRIDE + (k * 4 + w) * 1024);
        }
    };

    int cur = 0;
    stage(blk, 0);   // prologue

    for (int tile = blk; tile < ntiles; tile += nblk) {
        int tn = tile + nblk;
        if (tn < ntiles) stage(tn, cur ^ 1);
        // wait for THIS tile's batch (prev NCH gll); new batch stays in flight
        asm volatile("s_waitcnt vmcnt(%0)" ::"i"(NCH) : "memory");
        __builtin_amdgcn_s_barrier();
        __builtin_amdgcn_sched_barrier(0);

        // ---- GEMM1: h = relu(x @ W1 + b1), wave w -> cols [32w, 32w+32) ----
        const float* ab = (const float*)(sm + cur * ABUF_STRIDE);
#pragma unroll
        for (int rg = 0; rg < TM / 16; ++rg) {
            const int r = rg * 16 + l16;
            const int sw = r & 31;
            bf16x8 af[NKS];
#pragma unroll
            for (int ks = 0; ks < NKS; ++ks) {
                int c0 = (r << CRB) + ks * 8 + quad * 2;
                float4 v0 = *(const float4*)&ab[(size_t)(c0 ^ sw) * 4];
                float4 v1 = *(const float4*)&ab[(size_t)((c0 + 1) ^ sw) * 4];
                bf16x8 a;
                a[0] = (short)f2b(v0.x); a[1] = (short)f2b(v0.y);
                a[2] = (short)f2b(v0.z); a[3] = (short)f2b(v0.w);
                a[4] = (short)f2b(v1.x); a[5] = (short)f2b(v1.y);
                a[6] = (short)f2b(v1.z); a[7] = (short)f2b(v1.w);
                af[ks] = a;
            }
            f32x4 acc0 = (f32x4){0.f, 0.f, 0.f, 0.f};
            f32x4 acc1 = (f32x4){0.f, 0.f, 0.f, 0.f};
#pragma unroll
            for (int ks = 0; ks < NKS; ++ks) {
                acc0 = __builtin_amdgcn_mfma_f32_16x16x32_bf16(af[ks], b1f[0][ks], acc0, 0, 0, 0);
                acc1 = __builtin_amdgcn_mfma_f32_16x16x32_bf16(af[ks], b1f[1][ks], acc1, 0, 0, 0);
            }
#pragma unroll
            for (int r4 = 0; r4 < 4; ++r4) {
                int row = rg * 16 + quad * 4 + r4;
                h_s[row * SH + w * 32 + l16] = (short)f2b(fmaxf(acc0[r4] + bb1_0, 0.f));
                h_s[row * SH + w * 32 + 16 + l16] = (short)f2b(fmaxf(acc1[r4] + bb1_1, 0.f));
            }
        }
        asm volatile("s_waitcnt lgkmcnt(0)" ::: "memory");
        __builtin_amdgcn_s_barrier();
        __builtin_amdgcn_sched_barrier(0);

        // ---- GEMM2: p = h @ W2 (+bias2), wave w -> out cols [16w, 16w+16) ----
        const int base = tile * TM;
#pragma unroll
        for (int rg = 0; rg < TM / 16; ++rg) {
            f32x4 acc = (f32x4){0.f, 0.f, 0.f, 0.f};
#pragma unroll
            for (int ks = 0; ks < HID / 32; ++ks) {
                bf16x8 a = *(const bf16x8*)&h_s[(rg * 16 + l16) * SH + ks * 32 + quad * 8];
                acc = __builtin_amdgcn_mfma_f32_16x16x32_bf16(a, b2f[ks], acc, 0, 0, 0);
            }
#pragma unroll
            for (int r4 = 0; r4 < 4; ++r4) {
                int rr = base + rg * 16 + quad * 4 + r4;
                if (BF16OUT)
                    ((unsigned short*)outp)[(size_t)rr * OUTD + w * 16 + l16] = f2b(acc[r4]);
                else
                    ((float*)outp)[(size_t)rr * OUTD + w * 16 + l16] = acc[r4] + bb2;
            }
        }
        cur ^= 1;
    }
}

// ---------------------------------------------------------------------------
// Dual GEMM, persistent blocks: content [0, NBC), user [NBC, NBC+NBU).
// LDS: 2*32768 (fp32 A dbuf) + 32*SH*2 (h) = 74240 B -> 2 blocks/CU.
// ---------------------------------------------------------------------------
__global__ void __launch_bounds__(256, 2) dual_gemm(
    const float* __restrict__ xc, const __hip_bfloat16* __restrict__ Wc_p,
    const float* __restrict__ bc, const __hip_bfloat16* __restrict__ Wro_p,
    const float* __restrict__ b2, float* __restrict__ out,
    const float* __restrict__ xu, const __hip_bfloat16* __restrict__ Wu_p,
    const float* __restrict__ bu, const __hip_bfloat16* __restrict__ Wlo_p,
    unsigned short* __restrict__ pu) {
    __shared__ __align__(16) char sm[2 * ABUF_STRIDE + TM * SH * 2];
    int b = blockIdx.x;
    if (b < NBC)
        gemm_path<DC, false>(xc, Wc_p, bc, Wro_p, b2, out, NT_C, b, NBC, sm);
    else
        gemm_path<DU, true>(xu, Wu_p, bu, Wlo_p, nullptr, pu, NT_U, b - NBC, NBU, sm);
}

// ---------------------------------------------------------------------------
// Phase A: LDS-bucketed scatter of edges into NBUCK coarse buckets.
// ---------------------------------------------------------------------------
__global__ void __launch_bounds__(256) bucket_a(const int* __restrict__ src,
                                                const int* __restrict__ dst,
                                                int* __restrict__ gcur,
                                                unsigned int* __restrict__ bke) {
    __shared__ unsigned int pk[EPB];      // 32 KB
    __shared__ int hist[NBUCK];
    __shared__ int lbase[NBUCK];
    __shared__ int lcur[NBUCK];
    __shared__ int gb[NBUCK];
    __shared__ int ts[256];
    const int t = threadIdx.x;
    const int base = blockIdx.x * EPB;
    for (int i = t; i < NBUCK; i += 256) hist[i] = 0;
    __syncthreads();
#pragma unroll
    for (int k = 0; k < EPB / 256; ++k) {
        int e = base + k * 256 + t;
        if (e < NE) atomicAdd(&hist[dst[e] >> BSHIFT], 1);
    }
    __syncthreads();
    int h = (t < NBUCK) ? hist[t] : 0;
    ts[t] = h;
    __syncthreads();
    for (int d = 1; d < 256; d <<= 1) {
        int x = (t >= d) ? ts[t - d] : 0;
        __syncthreads();
        ts[t] += x;
        __syncthreads();
    }
    if (t < NBUCK) {
        int ex = ts[t] - h;
        lbase[t] = ex;
        lcur[t] = ex;
        gb[t] = atomicAdd(&gcur[t], h);
    }
    __syncthreads();
#pragma unroll
    for (int k = 0; k < EPB / 256; ++k) {
        int e = base + k * 256 + t;
        if (e < NE) {
            int s = src[e], d = dst[e];
            int b = d >> BSHIFT;
            int p = atomicAdd(&lcur[b], 1);
            pk[p] = ((unsigned int)s << BSHIFT) | (unsigned int)(d & (BRANGE - 1));
        }
    }
    __syncthreads();
    const int wv = t >> 6, ln = t & 63;
    for (int b = wv; b < NBUCK; b += 4) {
        int s0 = lbase[b], c = hist[b], g0 = gb[b];
        for (int j = ln; j < c; j += 64) {
            int pos = g0 + j;
            if (pos < BCAP) bke[(size_t)b * BCAP + pos] = pk[s0 + j];
        }
    }
}

// ---------------------------------------------------------------------------
// Mid: exclusive scan of bucket totals -> gbase; off[NC] = NE
// ---------------------------------------------------------------------------
__global__ void scan_mid(const int* __restrict__ gcur, int* __restrict__ gbase,
                         int* __restrict__ off) {
    __shared__ int ts[256];
    int t = threadIdx.x;
    int h = (t < NBUCK) ? gcur[t] : 0;
    ts[t] = h;
    __syncthreads();
    for (int d = 1; d < 256; d <<= 1) {
        int x = (t >= d) ? ts[t - d] : 0;
        __syncthreads();
        ts[t] += x;
        __syncthreads();
    }
    if (t < NBUCK) gbase[t] = ts[t] - h;
    if (t == 0) { gbase[NBUCK] = NE; off[NC] = NE; }
}

// ---------------------------------------------------------------------------
// Phase B: per-bucket counting sort in LDS -> off[] + ssrc[] (dense writes)
// ---------------------------------------------------------------------------
__global__ void __launch_bounds__(256) bucket_b(const int* __restrict__ gcur,
                                                const int* __restrict__ gbase,
                                                const unsigned int* __restrict__ bke,
                                                int* __restrict__ off,
                                                int* __restrict__ ssrc) {
    __shared__ unsigned int pk[BCAP];     // 40 KB
    __shared__ int hist[BRANGE];
    __shared__ int hb[BRANGE];
    __shared__ int cur[BRANGE];
    __shared__ int ts[256];
    const int t = threadIdx.x;
    const int b = blockIdx.x;
    const int n = min(gcur[b], BCAP);
    const int g0 = gbase[b];
    for (int i = t; i < n; i += 256) pk[i] = bke[(size_t)b * BCAP + i];
    for (int i = t; i < BRANGE; i += 256) hist[i] = 0;
    __syncthreads();
    for (int i = t; i < n; i += 256) atomicAdd(&hist[pk[i] & (BRANGE - 1)], 1);
    __syncthreads();
    int a0 = hist[2 * t], a1 = hist[2 * t + 1];
    int s = a0 + a1;
    ts[t] = s;
    __syncthreads();
    for (int d = 1; d < 256; d <<= 1) {
        int x = (t >= d) ? ts[t - d] : 0;
        __syncthreads();
        ts[t] += x;
        __syncthreads();
    }
    int ex = ts[t] - s;
    hb[2 * t] = ex;
    hb[2 * t + 1] = ex + a0;
    __syncthreads();
    for (int i = t; i < BRANGE; i += 256) {
        int node = b * BRANGE + i;
        cur[i] = g0 + hb[i];
        if (node < NC) off[node] = g0 + hb[i];
    }
    __syncthreads();
    for (int i = t; i < n; i += 256) {
        unsigned int v = pk[i];
        int p = atomicAdd(&cur[v & (BRANGE - 1)], 1);
        ssrc[p] = (int)(v >> BSHIFT);
    }
}

// ---------------------------------------------------------------------------
// Gather-aggregate (bf16 pu) + mean + add into out. One wave per node.
// ---------------------------------------------------------------------------
__global__ void __launch_bounds__(256) gather_agg(const int* __restrict__ ssrc,
                                                  const int* __restrict__ off,
                                                  const unsigned int* __restrict__ pu,
                                                  float* __restrict__ out) {
    int node = blockIdx.x * 4 + (threadIdx.x >> 6);
    if (node >= NC) return;
    int lane = threadIdx.x & 63;
    int g = lane >> 3;
    int f8 = lane & 7;
    int e0 = off[node], e1 = off[node + 1];
    float acc[8] = {0.f, 0.f, 0.f, 0.f, 0.f, 0.f, 0.f, 0.f};
    for (int e = e0 + g; e < e1; e += 8) {
        int s = ssrc[e];
        uint4 v = ((const uint4*)pu)[(size_t)s * 8 + f8];
        acc[0] += __uint_as_float(v.x << 16);
        acc[1] += __uint_as_float(v.x & 0xffff0000u);
        acc[2] += __uint_as_float(v.y << 16);
        acc[3] += __uint_as_float(v.y & 0xffff0000u);
        acc[4] += __uint_as_float(v.z << 16);
        acc[5] += __uint_as_float(v.z & 0xffff0000u);
        acc[6] += __uint_as_float(v.w << 16);
        acc[7] += __uint_as_float(v.w & 0xffff0000u);
    }
#pragma unroll
    for (int m = 8; m <= 32; m <<= 1) {
#pragma unroll
        for (int j = 0; j < 8; ++j) acc[j] += __shfl_xor(acc[j], m, 64);
    }
    if (g == 0) {
        float inv = 1.0f / (float)max(e1 - e0, 1);
        float4* po = (float4*)(out + (size_t)node * OUTD + f8 * 8);
        float4 o0 = po[0], o1 = po[1];
        o0.x += acc[0] * inv; o0.y += acc[1] * inv;
        o0.z += acc[2] * inv; o0.w += acc[3] * inv;
        o1.x += acc[4] * inv; o1.y += acc[5] * inv;
        o1.z += acc[6] * inv; o1.w += acc[7] * inv;
        po[0] = o0; po[1] = o1;
    }
}

extern "C" void kernel_launch(void* const* d_in, const int* in_sizes, int n_in,
                              void* d_out, int out_size, void* d_ws, size_t ws_size,
                              hipStream_t stream) {
    const float* xc = (const float*)d_in[0];
    const float* xu = (const float*)d_in[1];
    const int*   ei = (const int*)d_in[2];
    const float* Wc = (const float*)d_in[3];
    const float* bc = (const float*)d_in[4];
    const float* Wu = (const float*)d_in[5];
    const float* bu = (const float*)d_in[6];
    const float* Wl = (const float*)d_in[7];
    const float* bl = (const float*)d_in[8];
    const float* Wr = (const float*)d_in[9];
    const float* Wo = (const float*)d_in[10];
    const float* bo = (const float*)d_in[11];
    float* out = (float*)d_out;

    const int* esrc = ei;        // edge_index[0] = user ids
    const int* edst = ei + NE;   // edge_index[1] = content ids

    // workspace carve (all chunk sizes multiples of 16 B)
    unsigned short* pu = (unsigned short*)d_ws;             // NU*64 bf16 (12.8 MB)
    int* ssrc  = (int*)(pu + (size_t)NU * OUTD);            // NE (6.4 MB)
    unsigned int* bke = (unsigned int*)(ssrc + NE);         // NBUCK*BCAP (8.03 MB)
    int* gcur  = (int*)(bke + (size_t)NBUCK * BCAP);        // 196
    int* gbase = gcur + NBUCK;                              // 197 (pad to 400 total)
    int* off   = gcur + 400;                                // NC+1 (pad to NC+4)
    float* b2  = (float*)(off + NC + 4);                    // 64
    __hip_bfloat16* Wlo_p = (__hip_bfloat16*)(b2 + OUTD);   // 64*128
    __hip_bfloat16* Wro_p = Wlo_p + OUTD * HID;             // 64*128
    __hip_bfloat16* Wu_p  = Wro_p + OUTD * HID;             // 128*128
    __hip_bfloat16* Wc_p  = Wu_p + HID * DU;                // 128*256

    hipMemsetAsync(gcur, 0, NBUCK * sizeof(int), stream);

    prep_kernel<<<HID, OUTD, 0, stream>>>(Wl, bl, Wr, Wo, bo, Wlo_p, Wro_p, b2);
    pack_w<<<(DU * HID + 255) / 256, 256, 0, stream>>>(Wu, Wu_p, DU);
    pack_w<<<(DC * HID + 255) / 256, 256, 0, stream>>>(Wc, Wc_p, DC);

    dual_gemm<<<NBC + NBU, 256, 0, stream>>>(xc, Wc_p, bc, Wro_p, b2, out,
                                             xu, Wu_p, bu, Wlo_p, pu);

    bucket_a<<<ABLK, 256, 0, stream>>>(esrc, edst, gcur, bke);
    scan_mid<<<1, 256, 0, stream>>>(gcur, gbase, off);
    bucket_b<<<NBUCK, 256, 0, stream>>>(gcur, gbase, bke, off, ssrc);
    gather_agg<<<(NC + 3) / 4, 256, 0, stream>>>(ssrc, off, (const unsigned int*)pu, out);
}

// Round 4
// 334.087 us; speedup vs baseline: 1.0377x; 1.0377x over previous
//
#include <hip/hip_runtime.h>
#include <hip/hip_bf16.h>

#define NC 100000
#define NU 100000
#define NE 1600000
#define DC 256
#define DU 128
#define HID 128
#define OUTD 64

#define BSHIFT 9
#define BRANGE 512
#define NBUCK ((NC + BRANGE - 1) / BRANGE)   // 196
#define BCAP 10240
#define EPB 8192
#define ABLK ((NE + EPB - 1) / EPB)          // 196

#define TM 32                                // GEMM tile rows (NC, NU divisible)
#define NT_C (NC / TM)                       // 3125
#define NT_U (NU / TM)                       // 3125

#define SH (HID + 8)                         // h_s row stride (shorts)

typedef __attribute__((ext_vector_type(8))) short bf16x8;
typedef __attribute__((ext_vector_type(4))) float f32x4;

// RNE float->bf16 (finite inputs)
__device__ inline unsigned short f2b(float f) {
    unsigned int u = __float_as_uint(f);
    u += 0x7fffu + ((u >> 16) & 1u);
    return (unsigned short)(u >> 16);
}

// ---------------------------------------------------------------------------
// K0: Wlo_p = packed (Wl@Wo) bf16, Wro_p = packed (Wr@Wo) bf16, b2 = bl@Wo+bo.
// 4x K-split + LDS reduce (was 1 wave/block serial-K: latency-bound).
// Packed B-fragment layout for GEMM2 (16x16x32 mfma):
//   element W2[k][f]: idx = ((w*4 + ks)*64 + quad*16 + l16)*8 + e
//   with f = w*16+l16, k = ks*32 + quad*8 + e.
// ---------------------------------------------------------------------------
__global__ void prep_kernel(const float* __restrict__ Wl, const float* __restrict__ bl,
                            const float* __restrict__ Wr, const float* __restrict__ Wo,
                            const float* __restrict__ bo,
                            __hip_bfloat16* __restrict__ Wlo_p,
                            __hip_bfloat16* __restrict__ Wro_p,
                            float* __restrict__ b2) {
    const int k = blockIdx.x;          // 0..127 (HID)
    const int t = threadIdx.x;         // 0..255
    const int f = t & 63, j4 = t >> 6; // f: out col, j4: K-slice
    __shared__ float red[3][4][OUTD];
    float a0 = 0.f, a1 = 0.f, s = 0.f;
    for (int m = j4 * 32; m < j4 * 32 + 32; ++m) {
        float wo = Wo[m * OUTD + f];
        a0 = fmaf(Wl[k * HID + m], wo, a0);
        a1 = fmaf(Wr[k * HID + m], wo, a1);
        s = fmaf(bl[m], wo, s);
    }
    red[0][j4][f] = a0; red[1][j4][f] = a1; red[2][j4][f] = s;
    __syncthreads();
    if (j4 == 0) {
        a0 = red[0][0][f] + red[0][1][f] + red[0][2][f] + red[0][3][f];
        a1 = red[1][0][f] + red[1][1][f] + red[1][2][f] + red[1][3][f];
        const int wv = f >> 4, l16 = f & 15;
        const int ks = k >> 5, quad = (k >> 3) & 3, e = k & 7;
        const int idx = (((wv * 4 + ks) * 64) + quad * 16 + l16) * 8 + e;
        Wlo_p[idx] = __float2bfloat16(a0);
        Wro_p[idx] = __float2bfloat16(a1);
        if (k == 0)
            b2[f] = bo[f] + red[2][0][f] + red[2][1][f] + red[2][2][f] + red[2][3][f];
    }
}

// ---------------------------------------------------------------------------
// K0b: pack input-proj weight W[K][HID] into GEMM1 B-fragment-linear layout:
//   element W[k][j]: idx = (((j>>4)*(K/32) + (k>>5))*64 + ((k>>3)&3)*16 + (j&15))*8 + (k&7)
// ---------------------------------------------------------------------------
__global__ void pack_w(const float* __restrict__ W, __hip_bfloat16* __restrict__ Wp,
                       int K) {
    int i = blockIdx.x * blockDim.x + threadIdx.x;
    int total = K * HID;
    if (i >= total) return;
    int j = i % HID, k = i / HID;
    int nks = K >> 5;
    int idx = (((j >> 4) * nks + (k >> 5)) * 64 + ((k >> 3) & 3) * 16 + (j & 15)) * 8 +
              (k & 7);
    Wp[idx] = __float2bfloat16(W[k * HID + j]);
}

// ---------------------------------------------------------------------------
// Device GEMM path: p = relu(x @ W1 + b1) @ W2 (+bias2)
// Occupancy-first structure (R4): one 32-row tile per block, 25.6 KB LDS,
// launch_bounds(256,4) -> ~16 waves/CU. Cross-block TLP hides staging latency
// (blocks at different phases overlap); no intra-wave pipelining attempted.
// ---------------------------------------------------------------------------
template <int DIN, bool BF16OUT>
__device__ __forceinline__ void gemm_path(const float* __restrict__ x,
                                          const __hip_bfloat16* __restrict__ W1p,
                                          const float* __restrict__ b1,
                                          const __hip_bfloat16* __restrict__ W2p,
                                          const float* __restrict__ bias2,
                                          void* __restrict__ outp, int tile,
                                          short* __restrict__ smem) {
    constexpr int NKS = DIN / 32;        // GEMM1 K-steps
    constexpr int SA = DIN + 8;          // A row stride (shorts): +16B pad
    constexpr int CPR = DIN / 8;         // 8-float chunks per row
    constexpr int RSTEP = 256 / CPR;     // rows per 256-thread sweep
    constexpr int NCH = TM / RSTEP;      // sweeps (4 content / 2 user)
    short* a_s = smem;                   // [TM][SA]
    short* h_s = smem + TM * SA;         // [TM][SH]

    const int t = threadIdx.x;
    const int w = t >> 6, lane = t & 63;
    const int quad = lane >> 4, l16 = lane & 15;
    const int r0 = t / CPR, c0 = t % CPR;
    const int base = tile * TM;

    // ---- B fragments (packed, coalesced, L2-hot; loop-invariant per block) ----
    bf16x8 b1f[2][NKS];
#pragma unroll
    for (int ntl = 0; ntl < 2; ++ntl)
#pragma unroll
        for (int ks = 0; ks < NKS; ++ks)
            b1f[ntl][ks] =
                *(const bf16x8*)&W1p[(size_t)(((2 * w + ntl) * NKS + ks) * 64 + lane) * 8];
    bf16x8 b2f[HID / 32];
#pragma unroll
    for (int ks = 0; ks < HID / 32; ++ks)
        b2f[ks] = *(const bf16x8*)&W2p[(size_t)((w * 4 + ks) * 64 + lane) * 8];
    const float bb1_0 = b1[w * 32 + l16];
    const float bb1_1 = b1[w * 32 + 16 + l16];
    const float bb2 = BF16OUT ? 0.f : bias2[w * 16 + l16];

    // ---- stage A tile: coalesced fp32 loads -> f2b -> ds_write_b128 ----
    float4 va[NCH][2];
#pragma unroll
    for (int k = 0; k < NCH; ++k) {
        const float4* p = (const float4*)(x + (size_t)(base + r0 + k * RSTEP) * DIN + c0 * 8);
        va[k][0] = p[0];
        va[k][1] = p[1];
    }
#pragma unroll
    for (int k = 0; k < NCH; ++k) {
        bf16x8 a;
        a[0] = (short)f2b(va[k][0].x); a[1] = (short)f2b(va[k][0].y);
        a[2] = (short)f2b(va[k][0].z); a[3] = (short)f2b(va[k][0].w);
        a[4] = (short)f2b(va[k][1].x); a[5] = (short)f2b(va[k][1].y);
        a[6] = (short)f2b(va[k][1].z); a[7] = (short)f2b(va[k][1].w);
        *(bf16x8*)&a_s[(r0 + k * RSTEP) * SA + c0 * 8] = a;
    }
    __syncthreads();

    // ---- GEMM1: h = relu(x @ W1 + b1), wave w -> cols [32w, 32w+32) ----
#pragma unroll
    for (int rg = 0; rg < TM / 16; ++rg) {
        bf16x8 af[NKS];
#pragma unroll
        for (int ks = 0; ks < NKS; ++ks)
            af[ks] = *(const bf16x8*)&a_s[(rg * 16 + l16) * SA + ks * 32 + quad * 8];
        f32x4 acc0 = (f32x4){0.f, 0.f, 0.f, 0.f};
        f32x4 acc1 = (f32x4){0.f, 0.f, 0.f, 0.f};
#pragma unroll
        for (int ks = 0; ks < NKS; ++ks) {
            acc0 = __builtin_amdgcn_mfma_f32_16x16x32_bf16(af[ks], b1f[0][ks], acc0, 0, 0, 0);
            acc1 = __builtin_amdgcn_mfma_f32_16x16x32_bf16(af[ks], b1f[1][ks], acc1, 0, 0, 0);
        }
#pragma unroll
        for (int r = 0; r < 4; ++r) {
            int row = rg * 16 + quad * 4 + r;
            h_s[row * SH + w * 32 + l16] = (short)f2b(fmaxf(acc0[r] + bb1_0, 0.f));
            h_s[row * SH + w * 32 + 16 + l16] = (short)f2b(fmaxf(acc1[r] + bb1_1, 0.f));
        }
    }
    __syncthreads();

    // ---- GEMM2: p = h @ W2 (+bias2), wave w -> out cols [16w, 16w+16) ----
#pragma unroll
    for (int rg = 0; rg < TM / 16; ++rg) {
        f32x4 acc = (f32x4){0.f, 0.f, 0.f, 0.f};
#pragma unroll
        for (int ks = 0; ks < HID / 32; ++ks) {
            bf16x8 a = *(const bf16x8*)&h_s[(rg * 16 + l16) * SH + ks * 32 + quad * 8];
            acc = __builtin_amdgcn_mfma_f32_16x16x32_bf16(a, b2f[ks], acc, 0, 0, 0);
        }
#pragma unroll
        for (int r = 0; r < 4; ++r) {
            int rr = base + rg * 16 + quad * 4 + r;
            if (BF16OUT)
                ((unsigned short*)outp)[(size_t)rr * OUTD + w * 16 + l16] = f2b(acc[r]);
            else
                ((float*)outp)[(size_t)rr * OUTD + w * 16 + l16] = acc[r] + bb2;
        }
    }
}

// ---------------------------------------------------------------------------
// Dual GEMM: content blocks [0, NT_C), user blocks [NT_C, NT_C+NT_U).
// LDS: 32*(DC+8)*2 + 32*(HID+8)*2 = 25600 B -> 6 blocks/CU by LDS;
// launch_bounds(256,4) -> VGPR<=128, ~4 blocks (16 waves)/CU.
// ---------------------------------------------------------------------------
__global__ void __launch_bounds__(256, 4) dual_gemm(
    const float* __restrict__ xc, const __hip_bfloat16* __restrict__ Wc_p,
    const float* __restrict__ bc, const __hip_bfloat16* __restrict__ Wro_p,
    const float* __restrict__ b2, float* __restrict__ out,
    const float* __restrict__ xu, const __hip_bfloat16* __restrict__ Wu_p,
    const float* __restrict__ bu, const __hip_bfloat16* __restrict__ Wlo_p,
    unsigned short* __restrict__ pu) {
    __shared__ __align__(16) short smem[TM * (DC + 8) + TM * (HID + 8)];
    int b = blockIdx.x;
    if (b < NT_C)
        gemm_path<DC, false>(xc, Wc_p, bc, Wro_p, b2, out, b, smem);
    else
        gemm_path<DU, true>(xu, Wu_p, bu, Wlo_p, nullptr, pu, b - NT_C, smem);
}

// ---------------------------------------------------------------------------
// Phase A: LDS-bucketed scatter of edges into NBUCK coarse buckets.
// ---------------------------------------------------------------------------
__global__ void __launch_bounds__(256) bucket_a(const int* __restrict__ src,
                                                const int* __restrict__ dst,
                                                int* __restrict__ gcur,
                                                unsigned int* __restrict__ bke) {
    __shared__ unsigned int pk[EPB];      // 32 KB
    __shared__ int hist[NBUCK];
    __shared__ int lbase[NBUCK];
    __shared__ int lcur[NBUCK];
    __shared__ int gb[NBUCK];
    __shared__ int ts[256];
    const int t = threadIdx.x;
    const int base = blockIdx.x * EPB;
    for (int i = t; i < NBUCK; i += 256) hist[i] = 0;
    __syncthreads();
#pragma unroll
    for (int k = 0; k < EPB / 256; ++k) {
        int e = base + k * 256 + t;
        if (e < NE) atomicAdd(&hist[dst[e] >> BSHIFT], 1);
    }
    __syncthreads();
    int h = (t < NBUCK) ? hist[t] : 0;
    ts[t] = h;
    __syncthreads();
    for (int d = 1; d < 256; d <<= 1) {
        int x = (t >= d) ? ts[t - d] : 0;
        __syncthreads();
        ts[t] += x;
        __syncthreads();
    }
    if (t < NBUCK) {
        int ex = ts[t] - h;
        lbase[t] = ex;
        lcur[t] = ex;
        gb[t] = atomicAdd(&gcur[t], h);
    }
    __syncthreads();
#pragma unroll
    for (int k = 0; k < EPB / 256; ++k) {
        int e = base + k * 256 + t;
        if (e < NE) {
            int s = src[e], d = dst[e];
            int b = d >> BSHIFT;
            int p = atomicAdd(&lcur[b], 1);
            pk[p] = ((unsigned int)s << BSHIFT) | (unsigned int)(d & (BRANGE - 1));
        }
    }
    __syncthreads();
    const int wv = t >> 6, ln = t & 63;
    for (int b = wv; b < NBUCK; b += 4) {
        int s0 = lbase[b], c = hist[b], g0 = gb[b];
        for (int j = ln; j < c; j += 64) {
            int pos = g0 + j;
            if (pos < BCAP) bke[(size_t)b * BCAP + pos] = pk[s0 + j];
        }
    }
}

// ---------------------------------------------------------------------------
// Mid: exclusive scan of bucket totals -> gbase; off[NC] = NE
// ---------------------------------------------------------------------------
__global__ void scan_mid(const int* __restrict__ gcur, int* __restrict__ gbase,
                         int* __restrict__ off) {
    __shared__ int ts[256];
    int t = threadIdx.x;
    int h = (t < NBUCK) ? gcur[t] : 0;
    ts[t] = h;
    __syncthreads();
    for (int d = 1; d < 256; d <<= 1) {
        int x = (t >= d) ? ts[t - d] : 0;
        __syncthreads();
        ts[t] += x;
        __syncthreads();
    }
    if (t < NBUCK) gbase[t] = ts[t] - h;
    if (t == 0) { gbase[NBUCK] = NE; off[NC] = NE; }
}

// ---------------------------------------------------------------------------
// Phase B: per-bucket counting sort in LDS -> off[] + ssrc[] (dense writes)
// ---------------------------------------------------------------------------
__global__ void __launch_bounds__(256) bucket_b(const int* __restrict__ gcur,
                                                const int* __restrict__ gbase,
                                                const unsigned int* __restrict__ bke,
                                                int* __restrict__ off,
                                                int* __restrict__ ssrc) {
    __shared__ unsigned int pk[BCAP];     // 40 KB
    __shared__ int hist[BRANGE];
    __shared__ int hb[BRANGE];
    __shared__ int cur[BRANGE];
    __shared__ int ts[256];
    const int t = threadIdx.x;
    const int b = blockIdx.x;
    const int n = min(gcur[b], BCAP);
    const int g0 = gbase[b];
    for (int i = t; i < n; i += 256) pk[i] = bke[(size_t)b * BCAP + i];
    for (int i = t; i < BRANGE; i += 256) hist[i] = 0;
    __syncthreads();
    for (int i = t; i < n; i += 256) atomicAdd(&hist[pk[i] & (BRANGE - 1)], 1);
    __syncthreads();
    int a0 = hist[2 * t], a1 = hist[2 * t + 1];
    int s = a0 + a1;
    ts[t] = s;
    __syncthreads();
    for (int d = 1; d < 256; d <<= 1) {
        int x = (t >= d) ? ts[t - d] : 0;
        __syncthreads();
        ts[t] += x;
        __syncthreads();
    }
    int ex = ts[t] - s;
    hb[2 * t] = ex;
    hb[2 * t + 1] = ex + a0;
    __syncthreads();
    for (int i = t; i < BRANGE; i += 256) {
        int node = b * BRANGE + i;
        cur[i] = g0 + hb[i];
        if (node < NC) off[node] = g0 + hb[i];
    }
    __syncthreads();
    for (int i = t; i < n; i += 256) {
        unsigned int v = pk[i];
        int p = atomicAdd(&cur[v & (BRANGE - 1)], 1);
        ssrc[p] = (int)(v >> BSHIFT);
    }
}

// ---------------------------------------------------------------------------
// Gather-aggregate (bf16 pu) + mean + add into out. One wave per node.
// ---------------------------------------------------------------------------
__global__ void __launch_bounds__(256) gather_agg(const int* __restrict__ ssrc,
                                                  const int* __restrict__ off,
                                                  const unsigned int* __restrict__ pu,
                                                  float* __restrict__ out) {
    int node = blockIdx.x * 4 + (threadIdx.x >> 6);
    if (node >= NC) return;
    int lane = threadIdx.x & 63;
    int g = lane >> 3;
    int f8 = lane & 7;
    int e0 = off[node], e1 = off[node + 1];
    float acc[8] = {0.f, 0.f, 0.f, 0.f, 0.f, 0.f, 0.f, 0.f};
    for (int e = e0 + g; e < e1; e += 8) {
        int s = ssrc[e];
        uint4 v = ((const uint4*)pu)[(size_t)s * 8 + f8];
        acc[0] += __uint_as_float(v.x << 16);
        acc[1] += __uint_as_float(v.x & 0xffff0000u);
        acc[2] += __uint_as_float(v.y << 16);
        acc[3] += __uint_as_float(v.y & 0xffff0000u);
        acc[4] += __uint_as_float(v.z << 16);
        acc[5] += __uint_as_float(v.z & 0xffff0000u);
        acc[6] += __uint_as_float(v.w << 16);
        acc[7] += __uint_as_float(v.w & 0xffff0000u);
    }
#pragma unroll
    for (int m = 8; m <= 32; m <<= 1) {
#pragma unroll
        for (int j = 0; j < 8; ++j) acc[j] += __shfl_xor(acc[j], m, 64);
    }
    if (g == 0) {
        float inv = 1.0f / (float)max(e1 - e0, 1);
        float4* po = (float4*)(out + (size_t)node * OUTD + f8 * 8);
        float4 o0 = po[0], o1 = po[1];
        o0.x += acc[0] * inv; o0.y += acc[1] * inv;
        o0.z += acc[2] * inv; o0.w += acc[3] * inv;
        o1.x += acc[4] * inv; o1.y += acc[5] * inv;
        o1.z += acc[6] * inv; o1.w += acc[7] * inv;
        po[0] = o0; po[1] = o1;
    }
}

extern "C" void kernel_launch(void* const* d_in, const int* in_sizes, int n_in,
                              void* d_out, int out_size, void* d_ws, size_t ws_size,
                              hipStream_t stream) {
    const float* xc = (const float*)d_in[0];
    const float* xu = (const float*)d_in[1];
    const int*   ei = (const int*)d_in[2];
    const float* Wc = (const float*)d_in[3];
    const float* bc = (const float*)d_in[4];
    const float* Wu = (const float*)d_in[5];
    const float* bu = (const float*)d_in[6];
    const float* Wl = (const float*)d_in[7];
    const float* bl = (const float*)d_in[8];
    const float* Wr = (const float*)d_in[9];
    const float* Wo = (const float*)d_in[10];
    const float* bo = (const float*)d_in[11];
    float* out = (float*)d_out;

    const int* esrc = ei;        // edge_index[0] = user ids
    const int* edst = ei + NE;   // edge_index[1] = content ids

    // workspace carve (all chunk sizes multiples of 16 B)
    unsigned short* pu = (unsigned short*)d_ws;             // NU*64 bf16 (12.8 MB)
    int* ssrc  = (int*)(pu + (size_t)NU * OUTD);            // NE (6.4 MB)
    unsigned int* bke = (unsigned int*)(ssrc + NE);         // NBUCK*BCAP (8.03 MB)
    int* gcur  = (int*)(bke + (size_t)NBUCK * BCAP);        // 196
    int* gbase = gcur + NBUCK;                              // 197 (pad to 400 total)
    int* off   = gcur + 400;                                // NC+1 (pad to NC+4)
    float* b2  = (float*)(off + NC + 4);                    // 64
    __hip_bfloat16* Wlo_p = (__hip_bfloat16*)(b2 + OUTD);   // 64*128
    __hip_bfloat16* Wro_p = Wlo_p + OUTD * HID;             // 64*128
    __hip_bfloat16* Wu_p  = Wro_p + OUTD * HID;             // 128*128
    __hip_bfloat16* Wc_p  = Wu_p + HID * DU;                // 128*256

    hipMemsetAsync(gcur, 0, NBUCK * sizeof(int), stream);

    prep_kernel<<<HID, 256, 0, stream>>>(Wl, bl, Wr, Wo, bo, Wlo_p, Wro_p, b2);
    pack_w<<<(DU * HID + 255) / 256, 256, 0, stream>>>(Wu, Wu_p, DU);
    pack_w<<<(DC * HID + 255) / 256, 256, 0, stream>>>(Wc, Wc_p, DC);

    dual_gemm<<<NT_C + NT_U, 256, 0, stream>>>(xc, Wc_p, bc, Wro_p, b2, out,
                                               xu, Wu_p, bu, Wlo_p, pu);

    bucket_a<<<ABLK, 256, 0, stream>>>(esrc, edst, gcur, bke);
    scan_mid<<<1, 256, 0, stream>>>(gcur, gbase, off);
    bucket_b<<<NBUCK, 256, 0, stream>>>(gcur, gbase, bke, off, ssrc);
    gather_agg<<<(NC + 3) / 4, 256, 0, stream>>>(ssrc, off, (const unsigned int*)pu, out);
}